// Round 3
// baseline (1466.694 us; speedup 1.0000x reference)
//
#include <hip/hip_runtime.h>
#include <stdint.h>

typedef _Float16 f16;
typedef _Float16 f16x8 __attribute__((ext_vector_type(8)));
typedef _Float16 f16x4 __attribute__((ext_vector_type(4)));
typedef float f32x4 __attribute__((ext_vector_type(4)));
typedef int int4v __attribute__((ext_vector_type(4)));
typedef float float4v __attribute__((ext_vector_type(4)));

#define S_LEN 2048
#define D_DIM 64
#define QBLK 128
#define KBLK 64
#define NTHREADS 512
#define KSTEPS 32

__device__ __forceinline__ f16x8 cvt8(float4v a, float4v b) {
    f16x8 f;
    f[0]=(f16)a[0]; f[1]=(f16)a[1]; f[2]=(f16)a[2]; f[3]=(f16)a[3];
    f[4]=(f16)b[0]; f[5]=(f16)b[1]; f[6]=(f16)b[2]; f[7]=(f16)b[3];
    return f;
}
__device__ __forceinline__ uint32_t f16b(float x) {
    union { f16 h; uint16_t u; } c; c.h = (f16)x; return c.u;
}

__global__ __launch_bounds__(NTHREADS, 6)
void sdpa_kernel(const float* __restrict__ Qg, const float* __restrict__ Kg,
                 const float* __restrict__ Vg, const int* __restrict__ Mg,
                 float* __restrict__ ProbOut, float* __restrict__ AttnOut)
{
    // LDS: 16 KB (K dbuf) + 16 KB (Vt dbuf) = 32 KB -> 3 blocks/CU (24 waves)
    __shared__ f16 Klds[2][KBLK * D_DIM];    // [k][d], rows XOR-swizzled
    __shared__ f16 Vtlds[2][D_DIM * KBLK];   // [d][k], rows XOR-swizzled

    const int tid  = threadIdx.x;
    const int wq   = tid >> 6;
    const int lane = tid & 63;
    const int g    = lane >> 4;
    const int lr   = lane & 15;

    // XCD-aware swizzle: 128 consecutive logical blocks per XCD (~8 heads resident)
    const int wid = ((blockIdx.x & 7) << 7) + (blockIdx.x >> 3);
    const int bh  = wid >> 4;
    const int qb  = wid & 15;

    const size_t qkv_base = (size_t)bh * S_LEN * D_DIM;
    const size_t mat_base = (size_t)bh * S_LEN * S_LEN;
    const int qw0 = qb * QBLK + wq * 16;

    // ---- Q fragment: lane holds Q[qw0+lr][d = 8g+i+32h] (B-operand layout) ----
    f16x8 qfrag[2];
    {
        const float* qp = Qg + qkv_base + (size_t)(qw0 + lr) * D_DIM + g * 8;
        #pragma unroll
        for (int h = 0; h < 2; ++h)
            qfrag[h] = cvt8(*(const float4v*)(qp + 32 * h),
                            *(const float4v*)(qp + 32 * h + 4));
    }

    // staging assignments
    const int srow = tid >> 3, scol = (tid & 7) * 8;
    const int sidx = (srow * D_DIM + scol) ^ ((srow & 7) << 3);
    const int vrp  = tid >> 4, vdb = (tid & 15) * 4;

    const float* kbase = Kg + qkv_base;
    const float* vbase = Vg + qkv_base;
    const int*   mbase = Mg + mat_base + (size_t)(qw0 + lr) * S_LEN + 4 * g;

    // mask bits live in registers: 32 ksteps x 16 bits = 16 u32
    uint32_t mbits[16];
    #pragma unroll
    for (int i = 0; i < 16; ++i) mbits[i] = 0u;

    // ================= sweep 1: l = sum(exp(s)), record mask bits =================
    float lacc[4] = {0.f, 0.f, 0.f, 0.f};

    float4v ka, kb;
    {
        const float* kp = kbase + (size_t)srow * D_DIM + scol;
        ka = *(const float4v*)kp; kb = *(const float4v*)(kp + 4);
    }
    int4v mreg[4];
    #pragma unroll
    for (int ct = 0; ct < 4; ++ct)
        mreg[ct] = __builtin_nontemporal_load((const int4v*)(mbase + 16 * ct));
    *(f16x8*)&Klds[0][sidx] = cvt8(ka, kb);

    for (int t = 0; t < KSTEPS; ++t) {
        const int cur = t & 1;
        __syncthreads();
        // extract mask bits(t) from regs BEFORE MFMA, then immediately issue t+1
        // mask loads -> maximal in-flight distance before next barrier's vmcnt drain
        uint32_t bits = 0;
        #pragma unroll
        for (int ct = 0; ct < 4; ++ct) {
            #pragma unroll
            for (int r = 0; r < 4; ++r)
                bits |= (mreg[ct][r] != 0 ? 1u : 0u) << (4 * ct + r);
        }
        mbits[t >> 1] |= bits << ((t & 1) * 16);
        if (t + 1 < KSTEPS) {
            #pragma unroll
            for (int ct = 0; ct < 4; ++ct)
                mreg[ct] = __builtin_nontemporal_load(
                    (const int4v*)(mbase + (t + 1) * KBLK + 16 * ct));
            const float* kp = kbase + (size_t)((t + 1) * KBLK + srow) * D_DIM + scol;
            ka = *(const float4v*)kp; kb = *(const float4v*)(kp + 4);
        }
        // swapped QK^T: c[ct][r] = S[q=qw0+lr][k = t*64 + 16ct + 4g + r]
        f32x4 c[4];
        #pragma unroll
        for (int ct = 0; ct < 4; ++ct) {
            c[ct] = (f32x4){0.f, 0.f, 0.f, 0.f};
            #pragma unroll
            for (int h = 0; h < 2; ++h) {
                int rowl = 16 * ct + lr;
                int idx = (rowl * D_DIM + 8 * g + 32 * h) ^ ((rowl & 7) << 3);
                f16x8 kf = *(const f16x8*)(&Klds[cur][idx]);
                c[ct] = __builtin_amdgcn_mfma_f32_16x16x32_f16(kf, qfrag[h], c[ct], 0, 0, 0);
            }
        }
        #pragma unroll
        for (int ct = 0; ct < 4; ++ct) {
            #pragma unroll
            for (int r = 0; r < 4; ++r) {
                float s = c[ct][r] * 0.125f;
                float p = ((bits >> (4 * ct + r)) & 1) ? 0.f : __expf(s); // |s|<=8
                lacc[r] += p;
            }
        }
        if (t + 1 < KSTEPS)
            *(f16x8*)&Klds[cur ^ 1][sidx] = cvt8(ka, kb);
    }

    float lsum = (lacc[0] + lacc[1]) + (lacc[2] + lacc[3]);
    lsum += __shfl_xor(lsum, 16, 64);
    lsum += __shfl_xor(lsum, 32, 64);        // full row sum for q = qw0+lr
    const float inv_l = 1.f / lsum;

    // ================= sweep 2: recompute s, write attn, PV =================
    f32x4 acc[4];
    #pragma unroll
    for (int dt = 0; dt < 4; ++dt) acc[dt] = (f32x4){0.f, 0.f, 0.f, 0.f};

    float4v va, vb;
    {
        const float* kp = kbase + (size_t)srow * D_DIM + scol;
        ka = *(const float4v*)kp; kb = *(const float4v*)(kp + 4);
        const float* vp = vbase + (size_t)(2 * vrp) * D_DIM + vdb;
        va = *(const float4v*)vp; vb = *(const float4v*)(vp + D_DIM);
    }
    *(f16x8*)&Klds[0][sidx] = cvt8(ka, kb);
    #pragma unroll
    for (int j = 0; j < 4; ++j) {
        int d = vdb + j;
        uint32_t pk = f16b(va[j]) | (f16b(vb[j]) << 16);
        *(uint32_t*)&Vtlds[0][(d * KBLK + 2 * vrp) ^ ((d & 7) << 3)] = pk;
    }

    for (int t = 0; t < KSTEPS; ++t) {
        const int cur = t & 1;
        __syncthreads();
        if (t + 1 < KSTEPS) {
            const float* kp = kbase + (size_t)((t + 1) * KBLK + srow) * D_DIM + scol;
            ka = *(const float4v*)kp; kb = *(const float4v*)(kp + 4);
            const float* vp = vbase + (size_t)((t + 1) * KBLK + 2 * vrp) * D_DIM + vdb;
            va = *(const float4v*)vp; vb = *(const float4v*)(vp + D_DIM);
        }
        f32x4 c[4];
        #pragma unroll
        for (int ct = 0; ct < 4; ++ct) {
            c[ct] = (f32x4){0.f, 0.f, 0.f, 0.f};
            #pragma unroll
            for (int h = 0; h < 2; ++h) {
                int rowl = 16 * ct + lr;
                int idx = (rowl * D_DIM + 8 * g + 32 * h) ^ ((rowl & 7) << 3);
                f16x8 kf = *(const f16x8*)(&Klds[cur][idx]);
                c[ct] = __builtin_amdgcn_mfma_f32_16x16x32_f16(kf, qfrag[h], c[ct], 0, 0, 0);
            }
        }
        const uint32_t bits = mbits[t >> 1] >> ((t & 1) * 16);
        #pragma unroll
        for (int ct = 0; ct < 4; ++ct) {
            float4v av; f16x4 pa;
            #pragma unroll
            for (int r = 0; r < 4; ++r) {
                float s = c[ct][r] * 0.125f;
                float p = ((bits >> (4 * ct + r)) & 1) ? 0.f : __expf(s);
                float pn = p * inv_l;
                av[r] = pn; pa[r] = (f16)pn;
            }
            __builtin_nontemporal_store(av,
                (float4v*)(AttnOut + mat_base + (size_t)(qw0 + lr) * S_LEN
                           + t * KBLK + 16 * ct + 4 * g));
            // PV: C-layout (k=4g+r) IS the A-operand layout of 16x16x16 MFMA.
            // acc[dt] += P[q][k-chunk ct] * V[k-chunk ct][d-tile dt], in-register.
            #pragma unroll
            for (int dt = 0; dt < 4; ++dt) {
                int rowd = 16 * dt + lr;
                f16x4 vf = *(const f16x4*)&Vtlds[cur][(rowd * KBLK + 16 * ct + 4 * g)
                                                      ^ ((lr & 7) << 3)];
                acc[dt] = __builtin_amdgcn_mfma_f32_16x16x16f16(pa, vf, acc[dt], 0, 0, 0);
            }
        }
        if (t + 1 < KSTEPS) {
            *(f16x8*)&Klds[cur ^ 1][sidx] = cvt8(ka, kb);
            #pragma unroll
            for (int j = 0; j < 4; ++j) {
                int d = vdb + j;
                uint32_t pk = f16b(va[j]) | (f16b(vb[j]) << 16);
                *(uint32_t*)&Vtlds[cur ^ 1][(d * KBLK + 2 * vrp) ^ ((d & 7) << 3)] = pk;
            }
        }
    }

    // epilogue: prob (already normalized; C/D layout col=lr, row=4g+r)
    #pragma unroll
    for (int dt = 0; dt < 4; ++dt) {
        #pragma unroll
        for (int r = 0; r < 4; ++r) {
            int qrow = qw0 + 4 * g + r;
            ProbOut[qkv_base + (size_t)qrow * D_DIM + 16 * dt + lr] = acc[dt][r];
        }
    }
}

extern "C" void kernel_launch(void* const* d_in, const int* in_sizes, int n_in,
                              void* d_out, int out_size, void* d_ws, size_t ws_size,
                              hipStream_t stream)
{
    const float* Q = (const float*)d_in[0];
    const float* K = (const float*)d_in[1];
    const float* V = (const float*)d_in[2];
    const int*   M = (const int*)d_in[3];

    float* prob = (float*)d_out;                          // [4,16,2048,64]
    float* attn = prob + (size_t)4 * 16 * 2048 * 64;      // [4,16,2048,2048]

    dim3 grid(64 * (S_LEN / QBLK));   // 1024
    dim3 block(NTHREADS);
    sdpa_kernel<<<grid, block, 0, stream>>>(Q, K, V, M, prob, attn);
}

// Round 4
// 622.582 us; speedup vs baseline: 2.3558x; 2.3558x over previous
//
#include <hip/hip_runtime.h>
#include <stdint.h>

typedef _Float16 f16;
typedef _Float16 f16x8 __attribute__((ext_vector_type(8)));
typedef _Float16 f16x4 __attribute__((ext_vector_type(4)));
typedef float f32x4 __attribute__((ext_vector_type(4)));
typedef int int4v __attribute__((ext_vector_type(4)));
typedef float float4v __attribute__((ext_vector_type(4)));

#define S_LEN 2048
#define D_DIM 64
#define QBLK 128
#define KBLK 64
#define NTHREADS 512
#define KSTEPS 32

// Raw barrier: LDS-visibility only. Deliberately NO vmcnt drain — register-destined
// global loads and nontemporal attn stores stay in flight across the barrier (T4).
#define BARRIER() do { \
    asm volatile("s_waitcnt lgkmcnt(0)" ::: "memory"); \
    __builtin_amdgcn_s_barrier(); \
    asm volatile("" ::: "memory"); \
} while (0)

__device__ __forceinline__ f16x8 cvt8(float4v a, float4v b) {
    f16x8 f;
    f[0]=(f16)a[0]; f[1]=(f16)a[1]; f[2]=(f16)a[2]; f[3]=(f16)a[3];
    f[4]=(f16)b[0]; f[5]=(f16)b[1]; f[6]=(f16)b[2]; f[7]=(f16)b[3];
    return f;
}
__device__ __forceinline__ uint32_t f16b(float x) {
    union { f16 h; uint16_t u; } c; c.h = (f16)x; return c.u;
}

__global__ __launch_bounds__(NTHREADS, 4)
void sdpa_kernel(const float* __restrict__ Qg, const float* __restrict__ Kg,
                 const float* __restrict__ Vg, const int* __restrict__ Mg,
                 float* __restrict__ ProbOut, float* __restrict__ AttnOut)
{
    // LDS: 16 (K dbuf) + 16 (Vt dbuf) + 32 (mask bits) = 64 KB -> 2 blocks/CU
    __shared__ f16 Klds[2][KBLK * D_DIM];       // [k][d], rows XOR-swizzled
    __shared__ f16 Vtlds[2][D_DIM * KBLK];      // [d][k], rows XOR-swizzled
    __shared__ uint16_t Mw[KSTEPS][NTHREADS];   // packed mask bits (same-thread RW)

    const int tid  = threadIdx.x;
    const int lane = tid & 63;
    const int wq   = tid >> 6;
    const int g    = lane >> 4;
    const int lr   = lane & 15;

    // XCD-aware swizzle: 128 consecutive logical blocks per XCD
    const int wid = ((blockIdx.x & 7) << 7) + (blockIdx.x >> 3);
    const int bh  = wid >> 4;
    const int qb  = wid & 15;

    const size_t qkv_base = (size_t)bh * S_LEN * D_DIM;
    const size_t mat_base = (size_t)bh * S_LEN * S_LEN;
    const int qw0 = qb * QBLK + wq * 16;

    // ---- Q fragment: lane holds Q[qw0+lr][d = 8g+i+32h] (B-operand layout) ----
    f16x8 qfrag[2];
    {
        const float* qp = Qg + qkv_base + (size_t)(qw0 + lr) * D_DIM + g * 8;
        #pragma unroll
        for (int h = 0; h < 2; ++h)
            qfrag[h] = cvt8(*(const float4v*)(qp + 32 * h),
                            *(const float4v*)(qp + 32 * h + 4));
    }

    // staging assignments
    const int srow = tid >> 3, scol = (tid & 7) * 8;
    const int sidx = (srow * D_DIM + scol) ^ ((srow & 7) << 3);
    const int vrp  = tid >> 4, vdb = (tid & 15) * 4;

    const float* kbase = Kg + qkv_base;
    const float* vbase = Vg + qkv_base;
    const int*   mbase = Mg + mat_base + (size_t)(qw0 + lr) * S_LEN + 4 * g;

    // ================= sweep 1: l = sum(exp(s)), record mask bits =================
    float lacc[4] = {0.f, 0.f, 0.f, 0.f};

    float4v ka, kb;
    int4v mreg[4];
    {   // prologue: K loads first, then mask loads (K-before-M ordering)
        const float* kp = kbase + (size_t)srow * D_DIM + scol;
        ka = *(const float4v*)kp; kb = *(const float4v*)(kp + 4);
        #pragma unroll
        for (int ct = 0; ct < 4; ++ct)
            mreg[ct] = __builtin_nontemporal_load((const int4v*)(mbase + 16 * ct));
    }
    *(f16x8*)&Klds[0][sidx] = cvt8(ka, kb);

    for (int t = 0; t < KSTEPS; ++t) {
        const int cur = t & 1;
        BARRIER();
        // extract current mask bits (loads issued a full iteration ago -> landed)
        uint32_t bits = 0;
        #pragma unroll
        for (int ct = 0; ct < 4; ++ct) {
            #pragma unroll
            for (int r = 0; r < 4; ++r)
                bits |= (mreg[ct][r] != 0 ? 1u : 0u) << (4 * ct + r);
        }
        // issue next-tile loads: K FIRST, mask second (ds_write waits vmcnt(4), not 0)
        if (t + 1 < KSTEPS) {
            const float* kp = kbase + (size_t)((t + 1) * KBLK + srow) * D_DIM + scol;
            ka = *(const float4v*)kp; kb = *(const float4v*)(kp + 4);
            #pragma unroll
            for (int ct = 0; ct < 4; ++ct)
                mreg[ct] = __builtin_nontemporal_load(
                    (const int4v*)(mbase + (t + 1) * KBLK + 16 * ct));
        }
        // swapped QK^T: c[ct][r] = S[q=qw0+lr][k = 64t + 16ct + 4g + r]
        f32x4 c[4];
        #pragma unroll
        for (int ct = 0; ct < 4; ++ct) {
            c[ct] = (f32x4){0.f, 0.f, 0.f, 0.f};
            #pragma unroll
            for (int h = 0; h < 2; ++h) {
                int rowl = 16 * ct + lr;
                int idx = (rowl * D_DIM + 8 * g + 32 * h) ^ ((rowl & 7) << 3);
                f16x8 kf = *(const f16x8*)(&Klds[cur][idx]);
                c[ct] = __builtin_amdgcn_mfma_f32_16x16x32_f16(kf, qfrag[h], c[ct], 0, 0, 0);
            }
        }
        Mw[t][tid] = (uint16_t)bits;
        #pragma unroll
        for (int ct = 0; ct < 4; ++ct) {
            #pragma unroll
            for (int r = 0; r < 4; ++r) {
                float s = c[ct][r] * 0.125f;
                float p = ((bits >> (4 * ct + r)) & 1) ? 0.f : __expf(s); // |s|<=8
                lacc[r] += p;
            }
        }
        if (t + 1 < KSTEPS)
            *(f16x8*)&Klds[cur ^ 1][sidx] = cvt8(ka, kb);
    }

    float lsum = (lacc[0] + lacc[1]) + (lacc[2] + lacc[3]);
    lsum += __shfl_xor(lsum, 16, 64);
    lsum += __shfl_xor(lsum, 32, 64);        // full row sum for q = qw0+lr
    const float inv_l = 1.f / lsum;

    // ================= sweep 2: recompute s, write attn, PV =================
    f32x4 acc[4];
    #pragma unroll
    for (int dt = 0; dt < 4; ++dt) acc[dt] = (f32x4){0.f, 0.f, 0.f, 0.f};

    float4v va, vb;
    {   // prologue (safe: t=31 read buf1; last buf0 readers finished before t=31 barrier)
        const float* kp = kbase + (size_t)srow * D_DIM + scol;
        ka = *(const float4v*)kp; kb = *(const float4v*)(kp + 4);
        const float* vp = vbase + (size_t)(2 * vrp) * D_DIM + vdb;
        va = *(const float4v*)vp; vb = *(const float4v*)(vp + D_DIM);
    }
    *(f16x8*)&Klds[0][sidx] = cvt8(ka, kb);
    #pragma unroll
    for (int j = 0; j < 4; ++j) {
        int d = vdb + j;
        uint32_t pk = f16b(va[j]) | (f16b(vb[j]) << 16);
        *(uint32_t*)&Vtlds[0][(d * KBLK + 2 * vrp) ^ ((d & 7) << 3)] = pk;
    }

    for (int t = 0; t < KSTEPS; ++t) {
        const int cur = t & 1;
        BARRIER();
        if (t + 1 < KSTEPS) {
            const float* kp = kbase + (size_t)((t + 1) * KBLK + srow) * D_DIM + scol;
            ka = *(const float4v*)kp; kb = *(const float4v*)(kp + 4);
            const float* vp = vbase + (size_t)((t + 1) * KBLK + 2 * vrp) * D_DIM + vdb;
            va = *(const float4v*)vp; vb = *(const float4v*)(vp + D_DIM);
        }
        f32x4 c[4];
        #pragma unroll
        for (int ct = 0; ct < 4; ++ct) {
            c[ct] = (f32x4){0.f, 0.f, 0.f, 0.f};
            #pragma unroll
            for (int h = 0; h < 2; ++h) {
                int rowl = 16 * ct + lr;
                int idx = (rowl * D_DIM + 8 * g + 32 * h) ^ ((rowl & 7) << 3);
                f16x8 kf = *(const f16x8*)(&Klds[cur][idx]);
                c[ct] = __builtin_amdgcn_mfma_f32_16x16x32_f16(kf, qfrag[h], c[ct], 0, 0, 0);
            }
        }
        const uint32_t bits = Mw[t][tid];   // same-thread LDS, lgkm only
        #pragma unroll
        for (int ct = 0; ct < 4; ++ct) {
            float4v av; f16x4 pa;
            #pragma unroll
            for (int r = 0; r < 4; ++r) {
                float s = c[ct][r] * 0.125f;
                float p = ((bits >> (4 * ct + r)) & 1) ? 0.f : __expf(s);
                float pn = p * inv_l;
                av[r] = pn; pa[r] = (f16)pn;
            }
            __builtin_nontemporal_store(av,
                (float4v*)(AttnOut + mat_base + (size_t)(qw0 + lr) * S_LEN
                           + t * KBLK + 16 * ct + 4 * g));
            // in-register PV: C-layout (k=4g+r) IS the 16x16x16 A-operand layout
            #pragma unroll
            for (int dt = 0; dt < 4; ++dt) {
                int rowd = 16 * dt + lr;
                f16x4 vf = *(const f16x4*)&Vtlds[cur][(rowd * KBLK + 16 * ct + 4 * g)
                                                      ^ ((lr & 7) << 3)];
                acc[dt] = __builtin_amdgcn_mfma_f32_16x16x16f16(pa, vf, acc[dt], 0, 0, 0);
            }
        }
        if (t + 1 < KSTEPS) {
            *(f16x8*)&Klds[cur ^ 1][sidx] = cvt8(ka, kb);
            #pragma unroll
            for (int j = 0; j < 4; ++j) {
                int d = vdb + j;
                uint32_t pk = f16b(va[j]) | (f16b(vb[j]) << 16);
                *(uint32_t*)&Vtlds[cur ^ 1][(d * KBLK + 2 * vrp) ^ ((d & 7) << 3)] = pk;
            }
        }
    }

    // epilogue: prob (already normalized; C/D layout col=lr, row=4g+r)
    #pragma unroll
    for (int dt = 0; dt < 4; ++dt) {
        #pragma unroll
        for (int r = 0; r < 4; ++r) {
            int qrow = qw0 + 4 * g + r;
            ProbOut[qkv_base + (size_t)qrow * D_DIM + 16 * dt + lr] = acc[dt][r];
        }
    }
}

extern "C" void kernel_launch(void* const* d_in, const int* in_sizes, int n_in,
                              void* d_out, int out_size, void* d_ws, size_t ws_size,
                              hipStream_t stream)
{
    const float* Q = (const float*)d_in[0];
    const float* K = (const float*)d_in[1];
    const float* V = (const float*)d_in[2];
    const int*   M = (const int*)d_in[3];

    float* prob = (float*)d_out;                          // [4,16,2048,64]
    float* attn = prob + (size_t)4 * 16 * 2048 * 64;      // [4,16,2048,2048]

    dim3 grid(64 * (S_LEN / QBLK));   // 1024
    dim3 block(NTHREADS);
    sdpa_kernel<<<grid, block, 0, stream>>>(Q, K, V, M, prob, attn);
}

// Round 5
// 585.370 us; speedup vs baseline: 2.5056x; 1.0636x over previous
//
#include <hip/hip_runtime.h>
#include <stdint.h>

typedef _Float16 f16;
typedef _Float16 f16x8 __attribute__((ext_vector_type(8)));
typedef _Float16 f16x4 __attribute__((ext_vector_type(4)));
typedef float f32x4 __attribute__((ext_vector_type(4)));
typedef int int4v __attribute__((ext_vector_type(4)));
typedef float float4v __attribute__((ext_vector_type(4)));

#define S_LEN 2048
#define D_DIM 64
#define QBLK 128
#define KBLK 64
#define NTHREADS 512
#define KSTEPS 32

// LDS-visibility barrier only: no vmcnt drain, global loads/stores stay in flight (T4).
#define BARRIER() do { \
    asm volatile("s_waitcnt lgkmcnt(0)" ::: "memory"); \
    __builtin_amdgcn_s_barrier(); \
    asm volatile("" ::: "memory"); \
} while (0)

__device__ __forceinline__ f16x8 cvt8(float4v a, float4v b) {
    f16x8 f;
    f[0]=(f16)a[0]; f[1]=(f16)a[1]; f[2]=(f16)a[2]; f[3]=(f16)a[3];
    f[4]=(f16)b[0]; f[5]=(f16)b[1]; f[6]=(f16)b[2]; f[7]=(f16)b[3];
    return f;
}
__device__ __forceinline__ uint32_t f16b(float x) {
    union { f16 h; uint16_t u; } c; c.h = (f16)x; return c.u;
}

// One sweep-1 kstep. MREG is one of two static register sets (2-deep mask prefetch).
#define S1_BODY(T, MREG) do { \
    const int tt = ((T) + phase) & 31; \
    const int cur = (T) & 1; \
    BARRIER(); \
    uint32_t bits = 0; \
    _Pragma("unroll") \
    for (int ct = 0; ct < 4; ++ct) { \
        _Pragma("unroll") \
        for (int r = 0; r < 4; ++r) \
            bits |= (MREG[ct][r] != 0 ? 1u : 0u) << (4 * ct + r); \
    } \
    if ((T) + 1 < KSTEPS) {   /* K loads FIRST (ds_write waits these, not mask) */ \
        const int tn = ((T) + 1 + phase) & 31; \
        const float* kp = kbase + (size_t)(tn * KBLK + srow) * D_DIM + scol; \
        ka = *(const float4v*)kp; kb = *(const float4v*)(kp + 4); \
    } \
    if ((T) + 2 < KSTEPS) {   /* mask prefetch 2 ksteps ahead into same reg set */ \
        const int tm = ((T) + 2 + phase) & 31; \
        _Pragma("unroll") \
        for (int ct = 0; ct < 4; ++ct) \
            MREG[ct] = __builtin_nontemporal_load( \
                (const int4v*)(mbase + (size_t)tm * KBLK + 16 * ct)); \
    } \
    f32x4 c[4]; \
    _Pragma("unroll") \
    for (int ct = 0; ct < 4; ++ct) { \
        c[ct] = (f32x4){0.f, 0.f, 0.f, 0.f}; \
        _Pragma("unroll") \
        for (int h = 0; h < 2; ++h) { \
            int rowl = 16 * ct + lr; \
            int idx = (rowl * D_DIM + 8 * g + 32 * h) ^ ((rowl & 7) << 3); \
            f16x8 kf = *(const f16x8*)(&Klds[cur][idx]); \
            c[ct] = __builtin_amdgcn_mfma_f32_16x16x32_f16(kf, qfrag[h], c[ct], 0, 0, 0); \
        } \
    } \
    Mw[tt][tid] = (uint16_t)bits; \
    _Pragma("unroll") \
    for (int ct = 0; ct < 4; ++ct) { \
        _Pragma("unroll") \
        for (int r = 0; r < 4; ++r) { \
            float s = c[ct][r] * 0.125f; \
            float p = ((bits >> (4 * ct + r)) & 1) ? 0.f : __expf(s); /* |s|<=8 */ \
            lacc[r] += p; \
        } \
    } \
    if ((T) + 1 < KSTEPS) \
        *(f16x8*)&Klds[cur ^ 1][sidx] = cvt8(ka, kb); \
} while (0)

__global__ __launch_bounds__(NTHREADS, 4)
void sdpa_kernel(const float* __restrict__ Qg, const float* __restrict__ Kg,
                 const float* __restrict__ Vg, const int* __restrict__ Mg,
                 float* __restrict__ ProbOut, float* __restrict__ AttnOut)
{
    // LDS: 16 (K dbuf) + 16 (Vt dbuf) + 32 (mask bits) = 64 KB -> 2 blocks/CU
    __shared__ f16 Klds[2][KBLK * D_DIM];       // [k][d], rows XOR-swizzled
    __shared__ f16 Vtlds[2][D_DIM * KBLK];      // [d][k'], k'-permuted, rows XOR-swizzled
    __shared__ uint16_t Mw[KSTEPS][NTHREADS];   // packed mask bits (same-thread RW)

    const int tid  = threadIdx.x;
    const int lane = tid & 63;
    const int wq   = tid >> 6;
    const int g    = lane >> 4;
    const int lr   = lane & 15;

    // XCD-aware swizzle: 128 consecutive logical blocks per XCD
    const int wid = ((blockIdx.x & 7) << 7) + (blockIdx.x >> 3);
    const int bh  = wid >> 4;
    const int qb  = wid & 15;
    // phase-staggered k-ring: de-sync HBM bursts chip-wide; mostly bh-keyed so
    // blocks sharing K/V stay near-lockstep for L2 reuse
    const int phase = ((bh & 3) << 3) | ((qb & 1) << 2);

    const size_t qkv_base = (size_t)bh * S_LEN * D_DIM;
    const size_t mat_base = (size_t)bh * S_LEN * S_LEN;
    const int qw0 = qb * QBLK + wq * 16;

    // ---- Q fragment: lane holds Q[qw0+lr][d = 8g+i+32h] (B-operand layout) ----
    f16x8 qfrag[2];
    {
        const float* qp = Qg + qkv_base + (size_t)(qw0 + lr) * D_DIM + g * 8;
        #pragma unroll
        for (int h = 0; h < 2; ++h)
            qfrag[h] = cvt8(*(const float4v*)(qp + 32 * h),
                            *(const float4v*)(qp + 32 * h + 4));
    }

    // staging assignments
    const int srow = tid >> 3, scol = (tid & 7) * 8;
    const int sidx = (srow * D_DIM + scol) ^ ((srow & 7) << 3);
    const int vrp  = tid >> 4, vdb = (tid & 15) * 4;
    // V k-permutation: k=16ct+4g+r -> k' = r | ct<<2 | g<<4 (even k -> even k')
    const int vk   = 2 * vrp;
    const int vkp  = (vk & 3) | (((vk >> 4) & 3) << 2) | (((vk >> 2) & 3) << 4);

    const float* kbase = Kg + qkv_base;
    const float* vbase = Vg + qkv_base;
    const int*   mbase = Mg + mat_base + (size_t)(qw0 + lr) * S_LEN + 4 * g;

    // ================= sweep 1: l = sum(exp(s)), record mask bits =================
    float lacc[4] = {0.f, 0.f, 0.f, 0.f};

    float4v ka, kb;
    int4v mregA[4], mregB[4];
    {   // prologue: K(tile phase) -> LDS[0]; mask tiles phase, phase+1 -> regs
        const float* kp = kbase + (size_t)(phase * KBLK + srow) * D_DIM + scol;
        ka = *(const float4v*)kp; kb = *(const float4v*)(kp + 4);
        const int t1 = (phase + 1) & 31;
        #pragma unroll
        for (int ct = 0; ct < 4; ++ct) {
            mregA[ct] = __builtin_nontemporal_load(
                (const int4v*)(mbase + (size_t)phase * KBLK + 16 * ct));
            mregB[ct] = __builtin_nontemporal_load(
                (const int4v*)(mbase + (size_t)t1 * KBLK + 16 * ct));
        }
    }
    *(f16x8*)&Klds[0][sidx] = cvt8(ka, kb);

    for (int t2 = 0; t2 < KSTEPS; t2 += 2) {
        S1_BODY(t2, mregA);
        S1_BODY(t2 + 1, mregB);
    }

    float lsum = (lacc[0] + lacc[1]) + (lacc[2] + lacc[3]);
    lsum += __shfl_xor(lsum, 16, 64);
    lsum += __shfl_xor(lsum, 32, 64);        // full row sum for q = qw0+lr
    const float inv_l = 1.f / lsum;

    // ================= sweep 2: recompute s, write attn, PV =================
    f32x4 acc[4];
    #pragma unroll
    for (int dt = 0; dt < 4; ++dt) acc[dt] = (f32x4){0.f, 0.f, 0.f, 0.f};

    float4v va, vb;
    {   // prologue (t=31 of sweep 1 reads buf1; writing buf0 here is safe)
        const float* kp = kbase + (size_t)(phase * KBLK + srow) * D_DIM + scol;
        ka = *(const float4v*)kp; kb = *(const float4v*)(kp + 4);
        const float* vp = vbase + (size_t)(phase * KBLK + vk) * D_DIM + vdb;
        va = *(const float4v*)vp; vb = *(const float4v*)(vp + D_DIM);
    }
    *(f16x8*)&Klds[0][sidx] = cvt8(ka, kb);
    #pragma unroll
    for (int j = 0; j < 4; ++j) {
        int d = vdb + j;
        uint32_t pk = f16b(va[j]) | (f16b(vb[j]) << 16);
        *(uint32_t*)&Vtlds[0][(d * KBLK + vkp) ^ ((d & 7) << 3)] = pk;
    }

    for (int t = 0; t < KSTEPS; ++t) {
        const int tt  = (t + phase) & 31;
        const int cur = t & 1;
        BARRIER();
        if (t + 1 < KSTEPS) {
            const int tn = (t + 1 + phase) & 31;
            const float* kp = kbase + (size_t)(tn * KBLK + srow) * D_DIM + scol;
            ka = *(const float4v*)kp; kb = *(const float4v*)(kp + 4);
            const float* vp = vbase + (size_t)(tn * KBLK + vk) * D_DIM + vdb;
            va = *(const float4v*)vp; vb = *(const float4v*)(vp + D_DIM);
        }
        f32x4 c[4];
        #pragma unroll
        for (int ct = 0; ct < 4; ++ct) {
            c[ct] = (f32x4){0.f, 0.f, 0.f, 0.f};
            #pragma unroll
            for (int h = 0; h < 2; ++h) {
                int rowl = 16 * ct + lr;
                int idx = (rowl * D_DIM + 8 * g + 32 * h) ^ ((rowl & 7) << 3);
                f16x8 kf = *(const f16x8*)(&Klds[cur][idx]);
                c[ct] = __builtin_amdgcn_mfma_f32_16x16x32_f16(kf, qfrag[h], c[ct], 0, 0, 0);
            }
        }
        const uint32_t bits = Mw[tt][tid];   // same-thread LDS
        f16x4 pa[4];
        #pragma unroll
        for (int ct = 0; ct < 4; ++ct) {
            float4v av;
            #pragma unroll
            for (int r = 0; r < 4; ++r) {
                float s = c[ct][r] * 0.125f;
                float p = ((bits >> (4 * ct + r)) & 1) ? 0.f : __expf(s);
                float pn = p * inv_l;
                av[r] = pn; pa[ct][r] = (f16)pn;
            }
            __builtin_nontemporal_store(av,
                (float4v*)(AttnOut + mat_base + (size_t)(qw0 + lr) * S_LEN
                           + tt * KBLK + 16 * ct + 4 * g));
        }
        // PV via permuted V: per dt one b128 covers ct{0,1}, one covers ct{2,3}
        #pragma unroll
        for (int dt = 0; dt < 4; ++dt) {
            int row = 16 * dt + lr;
            f16x8 vfA = *(const f16x8*)&Vtlds[cur][(row * KBLK + 16 * g)      ^ ((lr & 7) << 3)];
            f16x8 vfB = *(const f16x8*)&Vtlds[cur][(row * KBLK + 16 * g + 8)  ^ ((lr & 7) << 3)];
            acc[dt] = __builtin_amdgcn_mfma_f32_16x16x16f16(
                pa[0], __builtin_shufflevector(vfA, vfA, 0, 1, 2, 3), acc[dt], 0, 0, 0);
            acc[dt] = __builtin_amdgcn_mfma_f32_16x16x16f16(
                pa[1], __builtin_shufflevector(vfA, vfA, 4, 5, 6, 7), acc[dt], 0, 0, 0);
            acc[dt] = __builtin_amdgcn_mfma_f32_16x16x16f16(
                pa[2], __builtin_shufflevector(vfB, vfB, 0, 1, 2, 3), acc[dt], 0, 0, 0);
            acc[dt] = __builtin_amdgcn_mfma_f32_16x16x16f16(
                pa[3], __builtin_shufflevector(vfB, vfB, 4, 5, 6, 7), acc[dt], 0, 0, 0);
        }
        if (t + 1 < KSTEPS) {
            *(f16x8*)&Klds[cur ^ 1][sidx] = cvt8(ka, kb);
            #pragma unroll
            for (int j = 0; j < 4; ++j) {
                int d = vdb + j;
                uint32_t pk = f16b(va[j]) | (f16b(vb[j]) << 16);
                *(uint32_t*)&Vtlds[cur ^ 1][(d * KBLK + vkp) ^ ((d & 7) << 3)] = pk;
            }
        }
    }

    // epilogue: prob (already normalized; C/D layout col=lr, row=4g+r)
    #pragma unroll
    for (int dt = 0; dt < 4; ++dt) {
        #pragma unroll
        for (int r = 0; r < 4; ++r) {
            int qrow = qw0 + 4 * g + r;
            ProbOut[qkv_base + (size_t)qrow * D_DIM + 16 * dt + lr] = acc[dt][r];
        }
    }
}

extern "C" void kernel_launch(void* const* d_in, const int* in_sizes, int n_in,
                              void* d_out, int out_size, void* d_ws, size_t ws_size,
                              hipStream_t stream)
{
    const float* Q = (const float*)d_in[0];
    const float* K = (const float*)d_in[1];
    const float* V = (const float*)d_in[2];
    const int*   M = (const int*)d_in[3];

    float* prob = (float*)d_out;                          // [4,16,2048,64]
    float* attn = prob + (size_t)4 * 16 * 2048 * 64;      // [4,16,2048,2048]

    dim3 grid(64 * (S_LEN / QBLK));   // 1024
    dim3 block(NTHREADS);
    sdpa_kernel<<<grid, block, 0, stream>>>(Q, K, V, M, prob, attn);
}